// Round 5
// baseline (43.344 us; speedup 1.0000x reference)
//
#include <hip/hip_runtime.h>
#include <math.h>

#define HH 2048
#define WW 2048
#define T 8

// Gaussian sigma=2, 5 taps, normalized
#define GW0 0.15246914402033867f
#define GW1 0.22184129554377693f
#define GW2 0.25137912086578894f

typedef float f2v __attribute__((ext_vector_type(2)));
typedef float f4 __attribute__((ext_vector_type(4)));

struct R6 { float v[6]; };
struct R4 { float v[4]; };

// h-gauss row for virtual lab row vr (vertical reflect), covering hx = xb-2 .. xb+3.
// Horizontal reflect fixed up in-register on the edge lanes.
__device__ __forceinline__ R6 hrow(const float* __restrict__ lab, int vr, int xb,
                                   bool edgew, bool le, bool re) {
    int r = vr < 0 ? -vr : (vr >= HH ? 2 * HH - 2 - vr : vr);
    const float* row = lab + (size_t)r * WW;
    f2v L0 = *(const f2v*)(row + max(xb - 4, 0));
    f2v L1 = *(const f2v*)(row + max(xb - 2, 0));
    f2v L2 = *(const f2v*)(row + xb);
    f2v L3 = *(const f2v*)(row + min(xb + 2, WW - 2));
    f2v L4 = *(const f2v*)(row + min(xb + 4, WW - 2));
    float w[10] = {L0.x, L0.y, L1.x, L1.y, L2.x, L2.y, L3.x, L3.y, L4.x, L4.y};
    if (edgew) {
        if (le) { w[0] = L4.x; w[1] = L3.y; w[2] = L3.x; w[3] = L2.y; }  // lab[-4..-1] = lab[4,3,2,1]
        if (re) { w[7] = L1.y; w[8] = L1.x; w[9] = L0.y; }               // lab[2049..2051] = lab[2045..2043]
    }
    R6 h;
    #pragma unroll
    for (int j = 0; j < 6; ++j)
        h.v[j] = GW0 * (w[j] + w[j + 4]) + GW1 * (w[j + 1] + w[j + 3]) + GW2 * w[j + 2];
    return h;
}

// Vertical gaussian -> blur row (6-wide), with x-clamp fixups (sobel replicate pad).
__device__ __forceinline__ R6 vg(const R6& a, const R6& b, const R6& c, const R6& d, const R6& e_,
                                 bool edgew, bool le, bool re) {
    R6 o;
    #pragma unroll
    for (int j = 0; j < 6; ++j)
        o.v[j] = GW0 * (a.v[j] + e_.v[j]) + GW1 * (b.v[j] + d.v[j]) + GW2 * c.v[j];
    if (edgew) {
        if (le) { o.v[0] = o.v[2]; o.v[1] = o.v[2]; }   // blur[-2],[-1] -> blur[0]
        if (re) { o.v[4] = o.v[3]; o.v[5] = o.v[3]; }   // blur[2048],[2049] -> blur[2047]
    }
    return o;
}

// First sobel: 6-wide blur rows -> 4-wide gx,gy (covering x = xb-1 .. xb+2),
// with x-clamp dup on edges for the second sobel.
__device__ __forceinline__ void sobel(const R6& u, const R6& m, const R6& d, R4& ox, R4& oy,
                                      bool edgew, bool le, bool re) {
    #pragma unroll
    for (int j = 0; j < 4; ++j) {
        ox.v[j] = ((u.v[j+2] - u.v[j]) + 2.f*(m.v[j+2] - m.v[j]) + (d.v[j+2] - d.v[j])) * 0.125f;
        oy.v[j] = ((d.v[j] - u.v[j]) + 2.f*(d.v[j+1] - u.v[j+1]) + (d.v[j+2] - u.v[j+2])) * 0.125f;
    }
    if (edgew) {
        if (le) { ox.v[0] = ox.v[1]; oy.v[0] = oy.v[1]; }   // gx[-1] -> gx[0]
        if (re) { ox.v[3] = ox.v[2]; oy.v[3] = oy.v[2]; }   // gx[2048] -> gx[2047]
    }
}

// e = exp(pred*10) row (6-wide, x = xb-2 .. xb+3), zero outside image.
__device__ __forceinline__ R6 erow(const float* __restrict__ pred, int ry, int xb,
                                   bool edgew, bool le, bool re) {
    R6 o;
    if (ry < 0 || ry >= HH) {           // wave-uniform
        #pragma unroll
        for (int j = 0; j < 6; ++j) o.v[j] = 0.f;
        return o;
    }
    const float* row = pred + (size_t)ry * WW;
    f2v E0 = *(const f2v*)(row + max(xb - 2, 0));
    f2v E1 = *(const f2v*)(row + xb);
    f2v E2 = *(const f2v*)(row + min(xb + 2, WW - 2));
    float w[6] = {E0.x, E0.y, E1.x, E1.y, E2.x, E2.y};
    #pragma unroll
    for (int j = 0; j < 6; ++j) o.v[j] = __expf(w[j] * 10.f);
    if (edgew) {
        if (le) { o.v[0] = 0.f; o.v[1] = 0.f; }
        if (re) { o.v[4] = 0.f; o.v[5] = 0.f; }
    }
    return o;
}

__global__ __launch_bounds__(256, 4) void steal_main(const float* __restrict__ pred,
                                                     const float* __restrict__ lab,
                                                     float* __restrict__ acc) {
    const int lane = threadIdx.x & 63;
    const int wid  = (blockIdx.x << 2) + (threadIdx.x >> 6);   // 0..4095
    const int sx = wid & 15;
    const int y0 = (wid >> 4) * T;
    const int xb = sx * 128 + lane * 2;
    const bool edgew = (sx == 0) || (sx == 15);                // wave-uniform
    const bool le = (sx == 0) && (lane == 0);
    const bool re = (sx == 15) && (lane == 63);

    const float T1f = 0.41421356237309503f;   // tan(pi/8)
    const float T3f = 2.41421356237309510f;   // tan(3pi/8)

    // ---------------- prime ----------------
    R6 A0 = hrow(lab, y0-4, xb, edgew, le, re);
    R6 A1 = hrow(lab, y0-3, xb, edgew, le, re);
    R6 A2 = hrow(lab, y0-2, xb, edgew, le, re);
    R6 A3 = hrow(lab, y0-1, xb, edgew, le, re);
    R6 H0 = hrow(lab, y0+0, xb, edgew, le, re);
    R6 H1 = hrow(lab, y0+1, xb, edgew, le, re);
    R6 H2 = hrow(lab, y0+2, xb, edgew, le, re);
    R6 H3 = hrow(lab, y0+3, xb, edgew, le, re);
    R6 bm2 = vg(A0, A1, A2, A3, H0, edgew, le, re);   // blur[y0-2]
    R6 bm1 = vg(A1, A2, A3, H0, H1, edgew, le, re);   // blur[y0-1]
    R6 b0  = vg(A2, A3, H0, H1, H2, edgew, le, re);   // blur[y0]
    R6 b1  = vg(A3, H0, H1, H2, H3, edgew, le, re);   // blur[y0+1]
    R4 gx0, gy0, gx1, gy1;
    if (y0 > 0) {
        sobel(bm2, bm1, b0, gx0, gy0, edgew, le, re); // gxgy[y0-1]
        sobel(bm1, b0,  b1, gx1, gy1, edgew, le, re); // gxgy[y0]
    } else {
        sobel(b0, b0, b1, gx1, gy1, edgew, le, re);   // gxgy[0] (y-clamp dup of blur[-1])
        gx0 = gx1; gy0 = gy1;                          // gxgy[-1] -> gxgy[0]
    }
    R6 e0 = erow(pred, y0-2, xb, edgew, le, re);
    R6 e1 = erow(pred, y0-1, xb, edgew, le, re);
    R6 e2 = erow(pred, y0+0, xb, edgew, le, re);
    R6 e3 = erow(pred, y0+1, xb, edgew, le, re);

    float lsum = 0.f;

    // ---------------- main loop: 8 output rows ----------------
    for (int i = 0; i < T; ++i) {
        const int y = y0 + i;

        R6 bn;                                          // blur[y+2]
        if (y + 2 < HH) {
            R6 hn = hrow(lab, y + 4, xb, edgew, le, re);
            bn = vg(H0, H1, H2, H3, hn, edgew, le, re);
            H0 = H1; H1 = H2; H2 = H3; H3 = hn;
        } else bn = b1;                                 // dup blur[H-1]

        R4 gxn, gyn;                                    // gxgy[y+1]
        if (y + 1 < HH) sobel(b0, b1, bn, gxn, gyn, edgew, le, re);
        else { gxn = gx1; gyn = gy1; }                  // dup gxgy[H-1]

        R6 en = erow(pred, y + 2, xb, edgew, le, re);   // e[y+2]

        f2v pc2 = *(const f2v*)(pred + (size_t)y * WW + xb);
        float pcv[2] = {pc2.x, pc2.y};

        #pragma unroll
        for (int k = 0; k < 2; ++k) {
            float gxx = ((gx0.v[k+2]-gx0.v[k]) + 2.f*(gx1.v[k+2]-gx1.v[k]) +
                         (gxn.v[k+2]-gxn.v[k])) * 0.125f;
            float gxy = ((gy0.v[k+2]-gy0.v[k]) + 2.f*(gy1.v[k+2]-gy1.v[k]) +
                         (gyn.v[k+2]-gyn.v[k])) * 0.125f;
            float gyy = ((gyn.v[k]-gy0.v[k]) + 2.f*(gyn.v[k+1]-gy0.v[k+1]) +
                         (gyn.v[k+2]-gy0.v[k+2])) * 0.125f;
            float sg = -(gxy + 1e-6f);
            float sgn = (sg > 0.f) ? 1.f : ((sg < 0.f) ? -1.f : 0.f);
            float rt = gyy * sgn * __builtin_amdgcn_rcpf(gxx + 1e-6f);

            float hs  = e2.v[k] + e2.v[k+1] + e2.v[k+2] + e2.v[k+3] + e2.v[k+4];
            float vs  = e0.v[k+2] + e1.v[k+2] + e2.v[k+2] + e3.v[k+2] + en.v[k+2];
            float dls = e0.v[k]   + e1.v[k+1] + e2.v[k+2] + e3.v[k+3] + en.v[k+4];
            float dcs = e0.v[k+4] + e1.v[k+3] + e2.v[k+2] + e3.v[k+1] + en.v[k];

            bool isH = (rt >= -T1f) && (rt < T1f);
            bool isL = (rt >=  T1f) && (rt < T3f);
            bool isC = (rt >= -T3f) && (rt < -T1f);
            bool has = isH || isL || isC || (rt >= T3f) || (rt < -T3f);  // false only for NaN
            float resp = isH ? hs : (isL ? dls : (isC ? dcs : vs));
            float lv = pcv[k] * 10.f - __logf(resp + 1e-6f);
            lsum += has ? lv : 0.f;
        }

        // rotate windows
        b0 = b1; b1 = bn;
        gx0 = gx1; gx1 = gxn; gy0 = gy1; gy1 = gyn;
        e0 = e1; e1 = e2; e2 = e3; e3 = en;
    }

    // ---------------- wave reduction ----------------
    #pragma unroll
    for (int off = 32; off; off >>= 1) lsum += __shfl_down(lsum, off, 64);
    if (lane == 0) acc[wid] = lsum;
}

__global__ __launch_bounds__(256) void steal_finalize(const float* __restrict__ acc,
                                                      float* __restrict__ out, int n) {
    __shared__ double sd[256];
    double a = 0.0;
    int n4 = n >> 2;
    for (int i = threadIdx.x; i < n4; i += 256) {
        f4 v = *(const f4*)(acc + i * 4);
        a += (double)v.x + (double)v.y + (double)v.z + (double)v.w;
    }
    for (int i = (n4 << 2) + threadIdx.x; i < n; i += 256) a += (double)acc[i];
    sd[threadIdx.x] = a;
    __syncthreads();
    for (int s = 128; s > 0; s >>= 1) {
        if (threadIdx.x < s) sd[threadIdx.x] += sd[threadIdx.x + s];
        __syncthreads();
    }
    if (threadIdx.x == 0) out[0] = (float)(-sd[0] / 4194304.0);
}

extern "C" void kernel_launch(void* const* d_in, const int* in_sizes, int n_in,
                              void* d_out, int out_size, void* d_ws, size_t ws_size,
                              hipStream_t stream) {
    const float* pred = (const float*)d_in[0];   // (1,1,2048,2048) f32
    const float* lab  = (const float*)d_in[1];   // (1,2048,2048) f32
    float* out = (float*)d_out;                  // scalar f32
    float* ws  = (float*)d_ws;

    const int nwaves = 16 * (HH / T);            // 4096 wave-jobs
    const int nblocks = nwaves / 4;              // 1024 blocks x 256 threads

    steal_main<<<nblocks, 256, 0, stream>>>(pred, lab, ws);
    steal_finalize<<<1, 256, 0, stream>>>(ws, out, nwaves);
}